// Round 1
// baseline (556.649 us; speedup 1.0000x reference)
//
#include <hip/hip_runtime.h>
#include <math.h>

#define RES 160
#define NSAMP 128
#define NEAR_T 0.1f
#define FAR_T 10.0f
#define STEP ((FAR_T - NEAR_T) / (float)(NSAMP - 1))

typedef float float4v __attribute__((ext_vector_type(4)));

__device__ __forceinline__ void sample_geom(
    const float ox, const float oy, const float oz,
    const float dx, const float dy, const float dz,
    const int s, int vidx[8], float w8[8])
{
    const float t = NEAR_T + STEP * (float)s;
    const float px = ox + t * dx, py = oy + t * dy, pz = oz + t * dz;
    float vx = (px + 1.0f) * 0.5f * (float)RES;
    float vy = (py + 1.0f) * 0.5f * (float)RES;
    float vz = (pz + 1.0f) * 0.5f * (float)RES;
    vx = fminf(fmaxf(vx, 0.0f), (float)(RES - 1));
    vy = fminf(fmaxf(vy, 0.0f), (float)(RES - 1));
    vz = fminf(fmaxf(vz, 0.0f), (float)(RES - 1));
    const float flx = floorf(vx), fly = floorf(vy), flz = floorf(vz);
    const int x0 = (int)flx, y0 = (int)fly, z0 = (int)flz;
    const int x1 = min(x0 + 1, RES - 1);
    const int y1 = min(y0 + 1, RES - 1);
    const int z1 = min(z0 + 1, RES - 1);
    const float fx = vx - flx, fy = vy - fly, fz = vz - flz;

    const float wx0 = 1.0f - fx, wx1 = fx;
    const float wy0 = 1.0f - fy, wy1 = fy;
    const float wz0 = 1.0f - fz, wz1 = fz;

    const int zy00 = (z0 * RES + y0) * RES;
    const int zy01 = (z0 * RES + y1) * RES;
    const int zy10 = (z1 * RES + y0) * RES;
    const int zy11 = (z1 * RES + y1) * RES;
    vidx[0] = zy00 + x0; w8[0] = wx0 * wy0 * wz0;
    vidx[1] = zy10 + x0; w8[1] = wx0 * wy0 * wz1;
    vidx[2] = zy01 + x0; w8[2] = wx0 * wy1 * wz0;
    vidx[3] = zy11 + x0; w8[3] = wx0 * wy1 * wz1;
    vidx[4] = zy00 + x1; w8[4] = wx1 * wy0 * wz0;
    vidx[5] = zy10 + x1; w8[5] = wx1 * wy0 * wz1;
    vidx[6] = zy01 + x1; w8[6] = wx1 * wy1 * wz0;
    vidx[7] = zy11 + x1; w8[7] = wx1 * wy1 * wz1;
}

__global__ __launch_bounds__(1024) void plenoxel_kernel(
    const float* __restrict__ ray_o,
    const float* __restrict__ ray_d,
    const float* __restrict__ density,
    const float* __restrict__ sh,
    float* __restrict__ out_rgb,    // [R,3]
    float* __restrict__ out_depth,  // [R]
    float* __restrict__ out_acc,    // [R]
    int R)
{
    const int r   = blockIdx.x;
    const int tid = threadIdx.x;    // 0..1023
    const int s   = tid >> 3;       // sample index 0..127
    const int e   = tid & 7;        // lane within 8-lane sample group
    const int lane = tid & 63;
    if (r >= R) return;

    __shared__ float  sdens[NSAMP];
    __shared__ float  swgt[NSAMP];
    __shared__ int    slist[NSAMP];
    __shared__ int    scnt[2];
    __shared__ float  w0tot;
    __shared__ float  partDA[2][2];   // depth, acc partials per epilogue-wave
    __shared__ float  partRGB[2][3];
    __shared__ float4v srgb[NSAMP];

    const float ox = ray_o[r * 3 + 0], oy = ray_o[r * 3 + 1], oz = ray_o[r * 3 + 2];
    const float dx = ray_d[r * 3 + 0], dy = ray_d[r * 3 + 1], dz = ray_d[r * 3 + 2];

    // per-ray SH deg-2 basis
    const float dn  = sqrtf(dx * dx + dy * dy + dz * dz);
    const float inv = 1.0f / (dn + 1e-8f);
    const float nx = dx * inv, ny = dy * inv, nz = dz * inv;
    const float b0 = 0.28209479177387814f;
    const float b1 = -0.48860251190291987f * ny;
    const float b2 =  0.48860251190291987f * nz;
    const float b3 = -0.48860251190291987f * nx;
    const float b4 =  1.0925484305920792f * nx * ny;
    const float b5 = -1.0925484305920792f * ny * nz;
    const float b6 =  0.31539156525252005f * (2.0f * nz * nz - nx * nx - ny * ny);
    const float b7 = -1.0925484305920792f * nx * nz;
    const float b8 =  0.5462742152960396f * (nx * nx - ny * ny);

    // per-lane channel-masked basis vectors (lane e covers SH row floats
    // [offE, offE+3]; row layout: 0-8 = ch0, 9-17 = ch1, 18-26 = ch2)
    float4v bLo = {0.f, 0.f, 0.f, 0.f}, bHi = {0.f, 0.f, 0.f, 0.f};
    int chLo = 3, chHi = 3;   // 3 = none
    switch (e) {
        case 0: bLo = (float4v){b0, b1, b2, b3}; chLo = 0; break;
        case 1: bLo = (float4v){b4, b5, b6, b7}; chLo = 0; break;
        case 2: bLo = (float4v){b8, 0.f, 0.f, 0.f}; bHi = (float4v){0.f, b0, b1, b2};
                chLo = 0; chHi = 1; break;
        case 3: bLo = (float4v){b3, b4, b5, b6}; chLo = 1; break;
        case 4: bLo = (float4v){b7, b8, 0.f, 0.f}; bHi = (float4v){0.f, 0.f, b0, b1};
                chLo = 1; chHi = 2; break;
        case 5: bLo = (float4v){b2, b3, b4, b5}; chLo = 2; break;
        case 6: bLo = (float4v){0.f, b6, b7, b8}; chLo = 2; break; // float 23 dup zeroed
        default: break;                                            // lane 7: no SH work
    }
    const int offE = (e >= 6) ? 23 : 4 * e;

    // ---------------- Phase A: density gather (cheap: 32 B/sample) ----------
    {
        int vidx[8]; float w8[8];
        sample_geom(ox, oy, oz, dx, dy, dz, s, vidx, w8);
        float vD = w8[e] * density[vidx[e]];
        #pragma unroll
        for (int m = 1; m < 8; m <<= 1) vD += __shfl_xor(vD, m, 64);
        if (e == 0) sdens[s] = vD;
    }
    __syncthreads();

    // ---------------- Transmittance scan + weights + compaction -------------
    float incl = 1.0f, alphaV = 0.0f, tsV = 0.0f, wgt = 0.0f;
    bool flag = false; int rank = 0;
    if (tid < NSAMP) {
        const float d = sdens[tid];
        tsV = NEAR_T + STEP * (float)tid;
        const float dist = ((tid == NSAMP - 1) ? 1e10f : STEP) * dn;
        alphaV = 1.0f - __expf(-fmaxf(d, 0.0f) * dist);
        const float om = 1.0f - alphaV + 1e-10f;
        incl = om;
        #pragma unroll
        for (int off = 1; off < 64; off <<= 1) {
            const float u = __shfl_up(incl, off, 64);
            incl *= (lane >= off) ? u : 1.0f;
        }
    }
    if (tid == 63) w0tot = incl;
    __syncthreads();

    if (tid < NSAMP) {
        float excl = __shfl_up(incl, 1, 64);
        if (lane == 0) excl = 1.0f;
        const float trans = (tid < 64) ? excl : excl * w0tot;
        wgt = alphaV * trans;
        swgt[tid] = wgt;
        // exact-zero skip: wgt == 0 contributes bitwise nothing to rgb
        flag = (wgt != 0.0f);
        const unsigned long long mask = __ballot(flag);
        rank = __popcll(mask & ((1ull << lane) - 1ull));
        if (lane == 0) scnt[tid >> 6] = __popcll(mask);
        // depth & acc over ALL samples (identical numerics to before)
        float u3 = wgt * tsV, u4 = wgt;
        #pragma unroll
        for (int off = 32; off > 0; off >>= 1) {
            u3 += __shfl_down(u3, off, 64);
            u4 += __shfl_down(u4, off, 64);
        }
        if (lane == 0) { partDA[tid >> 6][0] = u3; partDA[tid >> 6][1] = u4; }
    }
    __syncthreads();

    if (tid < NSAMP && flag) {
        const int base = (tid >= 64) ? scnt[0] : 0;
        slist[base + rank] = tid;
    }
    __syncthreads();
    const int S = scnt[0] + scnt[1];   // survivor count (~50% on this data)

    // ---------------- Phase B: SH gather for survivors only -----------------
    const int g = tid >> 3;
    float rgb0 = 0.f, rgb1 = 0.f, rgb2 = 0.f;
    if (g < S) {
        const int s2 = slist[g];
        int vidx[8]; float w8[8];
        sample_geom(ox, oy, oz, dx, dy, dz, s2, vidx, w8);

        float accLo = 0.0f, accHi = 0.0f;
        if (e < 7) {   // lane 7's basis mask is all-zero: skip its 8 dead loads
            #pragma unroll
            for (int k = 0; k < 8; ++k) {
                const float* p = sh + (size_t)vidx[k] * 27 + offE;
                float4v row = *(const float4v*)p;   // 4B-aligned dwordx4 (HW unaligned OK)
                const float tl = row.x * bLo.x + row.y * bLo.y + row.z * bLo.z + row.w * bLo.w;
                const float th = row.x * bHi.x + row.y * bHi.y + row.z * bHi.z + row.w * bHi.w;
                accLo = fmaf(tl, w8[k], accLo);
                accHi = fmaf(th, w8[k], accHi);
            }
        }
        float v0 = ((chLo == 0) ? accLo : 0.0f) + ((chHi == 0) ? accHi : 0.0f);
        float v1 = ((chLo == 1) ? accLo : 0.0f) + ((chHi == 1) ? accHi : 0.0f);
        float v2 = ((chLo == 2) ? accLo : 0.0f) + ((chHi == 2) ? accHi : 0.0f);
        #pragma unroll
        for (int m = 1; m < 8; m <<= 1) {
            v0 += __shfl_xor(v0, m, 64);
            v1 += __shfl_xor(v1, m, 64);
            v2 += __shfl_xor(v2, m, 64);
        }
        if (e == 0) {
            const float wg = swgt[s2];
            rgb0 = wg * (1.0f / (1.0f + __expf(-v0)));
            rgb1 = wg * (1.0f / (1.0f + __expf(-v1)));
            rgb2 = wg * (1.0f / (1.0f + __expf(-v2)));
        }
    }
    if (e == 0) srgb[g] = (float4v){rgb0, rgb1, rgb2, 0.f};
    __syncthreads();

    // ---------------- Final rgb reduction over 128 groups -------------------
    if (tid < NSAMP) {
        const float4v dd = srgb[tid];
        float u0 = dd.x, u1 = dd.y, u2 = dd.z;
        #pragma unroll
        for (int off = 32; off > 0; off >>= 1) {
            u0 += __shfl_down(u0, off, 64);
            u1 += __shfl_down(u1, off, 64);
            u2 += __shfl_down(u2, off, 64);
        }
        if (lane == 0) {
            const int wv = tid >> 6;
            partRGB[wv][0] = u0; partRGB[wv][1] = u1; partRGB[wv][2] = u2;
        }
    }
    __syncthreads();
    if (tid == 0) {
        out_rgb[r * 3 + 0] = partRGB[0][0] + partRGB[1][0];
        out_rgb[r * 3 + 1] = partRGB[0][1] + partRGB[1][1];
        out_rgb[r * 3 + 2] = partRGB[0][2] + partRGB[1][2];
        out_depth[r]       = partDA[0][0] + partDA[1][0];
        out_acc[r]         = partDA[0][1] + partDA[1][1];
    }
}

extern "C" void kernel_launch(void* const* d_in, const int* in_sizes, int n_in,
                              void* d_out, int out_size, void* d_ws, size_t ws_size,
                              hipStream_t stream) {
    const float* ray_o   = (const float*)d_in[0];
    const float* ray_d   = (const float*)d_in[1];
    const float* density = (const float*)d_in[2];
    const float* sh      = (const float*)d_in[3];
    const int R = in_sizes[0] / 3;

    float* out_rgb   = (float*)d_out;
    float* out_depth = out_rgb + (size_t)R * 3;
    float* out_acc   = out_depth + R;

    plenoxel_kernel<<<R, 1024, 0, stream>>>(ray_o, ray_d, density, sh,
                                            out_rgb, out_depth, out_acc, R);
}

// Round 2
// 517.007 us; speedup vs baseline: 1.0767x; 1.0767x over previous
//
#include <hip/hip_runtime.h>
#include <math.h>

#define RES 160
#define NSAMP 128
#define NEAR_T 0.1f
#define FAR_T 10.0f
#define STEP ((FAR_T - NEAR_T) / (float)(NSAMP - 1))

typedef float float4v __attribute__((ext_vector_type(4)));

// corner k: xb = k>>2, yb = (k>>1)&1, zb = k&1 (reference order)
__device__ __forceinline__ void sample_geom8(
    const float ox, const float oy, const float oz,
    const float dx, const float dy, const float dz,
    const int s, int vidx[8], float w8[8])
{
    const float t = NEAR_T + STEP * (float)s;
    const float px = ox + t * dx, py = oy + t * dy, pz = oz + t * dz;
    float vx = (px + 1.0f) * 0.5f * (float)RES;
    float vy = (py + 1.0f) * 0.5f * (float)RES;
    float vz = (pz + 1.0f) * 0.5f * (float)RES;
    vx = fminf(fmaxf(vx, 0.0f), (float)(RES - 1));
    vy = fminf(fmaxf(vy, 0.0f), (float)(RES - 1));
    vz = fminf(fmaxf(vz, 0.0f), (float)(RES - 1));
    const float flx = floorf(vx), fly = floorf(vy), flz = floorf(vz);
    const int x0 = (int)flx, y0 = (int)fly, z0 = (int)flz;
    const int x1 = min(x0 + 1, RES - 1);
    const int y1 = min(y0 + 1, RES - 1);
    const int z1 = min(z0 + 1, RES - 1);
    const float fx = vx - flx, fy = vy - fly, fz = vz - flz;

    const float wx0 = 1.0f - fx, wx1 = fx;
    const float wy0 = 1.0f - fy, wy1 = fy;
    const float wz0 = 1.0f - fz, wz1 = fz;

    const int zy00 = (z0 * RES + y0) * RES;
    const int zy01 = (z0 * RES + y1) * RES;
    const int zy10 = (z1 * RES + y0) * RES;
    const int zy11 = (z1 * RES + y1) * RES;
    vidx[0] = zy00 + x0; w8[0] = wx0 * wy0 * wz0;
    vidx[1] = zy10 + x0; w8[1] = wx0 * wy0 * wz1;
    vidx[2] = zy01 + x0; w8[2] = wx0 * wy1 * wz0;
    vidx[3] = zy11 + x0; w8[3] = wx0 * wy1 * wz1;
    vidx[4] = zy00 + x1; w8[4] = wx1 * wy0 * wz0;
    vidx[5] = zy10 + x1; w8[5] = wx1 * wy0 * wz1;
    vidx[6] = zy01 + x1; w8[6] = wx1 * wy1 * wz0;
    vidx[7] = zy11 + x1; w8[7] = wx1 * wy1 * wz1;
}

// One ray per 64-lane wave. Single-wave workgroup: __syncthreads() carries no
// s_barrier cost (wave is lock-step); it only orders the LDS traffic.
__global__ __launch_bounds__(64) void plenoxel_kernel(
    const float* __restrict__ ray_o,
    const float* __restrict__ ray_d,
    const float* __restrict__ density,
    const float* __restrict__ sh,
    float* __restrict__ out_rgb,    // [R,3]
    float* __restrict__ out_depth,  // [R]
    float* __restrict__ out_acc,    // [R]
    int R)
{
    const int r    = blockIdx.x;
    const int lane = threadIdx.x;   // 0..63
    const int g    = lane >> 3;     // SH group 0..7
    const int e    = lane & 7;      // lane within SH group
    if (r >= R) return;

    __shared__ float swgt[NSAMP];
    __shared__ int   slist[NSAMP];

    const float ox = ray_o[r * 3 + 0], oy = ray_o[r * 3 + 1], oz = ray_o[r * 3 + 2];
    const float dx = ray_d[r * 3 + 0], dy = ray_d[r * 3 + 1], dz = ray_d[r * 3 + 2];

    // per-ray SH deg-2 basis (wave-uniform)
    const float dn  = sqrtf(dx * dx + dy * dy + dz * dz);
    const float inv = 1.0f / (dn + 1e-8f);
    const float nx = dx * inv, ny = dy * inv, nz = dz * inv;
    const float b0 = 0.28209479177387814f;
    const float b1 = -0.48860251190291987f * ny;
    const float b2 =  0.48860251190291987f * nz;
    const float b3 = -0.48860251190291987f * nx;
    const float b4 =  1.0925484305920792f * nx * ny;
    const float b5 = -1.0925484305920792f * ny * nz;
    const float b6 =  0.31539156525252005f * (2.0f * nz * nz - nx * nx - ny * ny);
    const float b7 = -1.0925484305920792f * nx * nz;
    const float b8 =  0.5462742152960396f * (nx * nx - ny * ny);

    // per-lane channel-masked basis vectors (lane e covers SH row floats
    // [offE, offE+3]; row layout: 0-8 = ch0, 9-17 = ch1, 18-26 = ch2)
    float4v bLo = {0.f, 0.f, 0.f, 0.f}, bHi = {0.f, 0.f, 0.f, 0.f};
    int chLo = 3, chHi = 3;   // 3 = none
    switch (e) {
        case 0: bLo = (float4v){b0, b1, b2, b3}; chLo = 0; break;
        case 1: bLo = (float4v){b4, b5, b6, b7}; chLo = 0; break;
        case 2: bLo = (float4v){b8, 0.f, 0.f, 0.f}; bHi = (float4v){0.f, b0, b1, b2};
                chLo = 0; chHi = 1; break;
        case 3: bLo = (float4v){b3, b4, b5, b6}; chLo = 1; break;
        case 4: bLo = (float4v){b7, b8, 0.f, 0.f}; bHi = (float4v){0.f, 0.f, b0, b1};
                chLo = 1; chHi = 2; break;
        case 5: bLo = (float4v){b2, b3, b4, b5}; chLo = 2; break;
        case 6: bLo = (float4v){0.f, b6, b7, b8}; chLo = 2; break; // float 23 dup zeroed
        default: break;                                            // lane 7: no SH work
    }
    const int offE = (e >= 6) ? 23 : 4 * e;

    // ---- Phase A: density. Lane l owns samples 2l, 2l+1 (registers, no LDS).
    float d0 = 0.0f, d1 = 0.0f;
    {
        int vA[8], vB[8]; float wA[8], wB[8];
        sample_geom8(ox, oy, oz, dx, dy, dz, 2 * lane,     vA, wA);
        sample_geom8(ox, oy, oz, dx, dy, dz, 2 * lane + 1, vB, wB);
        #pragma unroll
        for (int k = 0; k < 8; ++k) d0 = fmaf(wA[k], density[vA[k]], d0);
        #pragma unroll
        for (int k = 0; k < 8; ++k) d1 = fmaf(wB[k], density[vB[k]], d1);
    }

    // ---- Transmittance: 64-lane scan of pair-products (in-register) --------
    const float t0 = NEAR_T + STEP * (float)(2 * lane);
    const float t1 = t0 + STEP;
    const float dist0 = STEP * dn;
    const float dist1 = ((lane == 63) ? 1e10f : STEP) * dn;   // sample 127
    const float a0 = 1.0f - __expf(-fmaxf(d0, 0.0f) * dist0);
    const float a1 = 1.0f - __expf(-fmaxf(d1, 0.0f) * dist1);
    const float om0 = 1.0f - a0 + 1e-10f;
    const float om1 = 1.0f - a1 + 1e-10f;

    float incl = om0 * om1;
    #pragma unroll
    for (int off = 1; off < 64; off <<= 1) {
        const float u = __shfl_up(incl, off, 64);
        incl *= (lane >= off) ? u : 1.0f;
    }
    float excl = __shfl_up(incl, 1, 64);      // trans at sample 2l
    if (lane == 0) excl = 1.0f;
    const float w0 = a0 * excl;
    const float w1 = a1 * excl * om0;         // trans at 2l+1 = excl*om0

    // depth/acc partials (all samples — numerically exact w.r.t. skip)
    float accD = w0 * t0 + w1 * t1;
    float accA = w0 + w1;

    // ---- survivor compaction (exact-zero skip; wave-private, barrier-free) -
    const bool f0 = (w0 != 0.0f), f1 = (w1 != 0.0f);
    const unsigned long long m0 = __ballot(f0);
    const unsigned long long m1 = __ballot(f1);
    const unsigned long long below = (1ull << lane) - 1ull;
    const int nb = __popcll(m0 & below) + __popcll(m1 & below);
    const int S  = __popcll(m0) + __popcll(m1);
    if (f0) slist[nb] = 2 * lane;
    if (f1) slist[nb + (f0 ? 1 : 0)] = 2 * lane + 1;
    swgt[2 * lane]     = w0;
    swgt[2 * lane + 1] = w1;
    __syncthreads();   // single-wave workgroup: lgkmcnt ordering only

    // ---- Phase B: SH gather, 8-lane groups over survivors only -------------
    float rgb0 = 0.f, rgb1 = 0.f, rgb2 = 0.f;
    const int nIter = (S + 7) >> 3;
    for (int i = 0; i < nIter; ++i) {
        const int gi = i * 8 + g;
        const int s2 = (gi < S) ? slist[gi] : slist[0];   // S>0 here
        int vidx[8]; float w8[8];
        sample_geom8(ox, oy, oz, dx, dy, dz, s2, vidx, w8);

        float accLo = 0.0f, accHi = 0.0f;
        if (e < 7 && gi < S) {   // lane 7 basis is all-zero: skip dead loads
            #pragma unroll
            for (int k = 0; k < 8; ++k) {
                const float* p = sh + (size_t)vidx[k] * 27 + offE;
                float4v row = *(const float4v*)p;   // 4B-aligned dwordx4 (HW unaligned OK)
                const float tl = row.x * bLo.x + row.y * bLo.y + row.z * bLo.z + row.w * bLo.w;
                const float th = row.x * bHi.x + row.y * bHi.y + row.z * bHi.z + row.w * bHi.w;
                accLo = fmaf(tl, w8[k], accLo);
                accHi = fmaf(th, w8[k], accHi);
            }
        }
        float v0 = ((chLo == 0) ? accLo : 0.0f) + ((chHi == 0) ? accHi : 0.0f);
        float v1 = ((chLo == 1) ? accLo : 0.0f) + ((chHi == 1) ? accHi : 0.0f);
        float v2 = ((chLo == 2) ? accLo : 0.0f) + ((chHi == 2) ? accHi : 0.0f);
        #pragma unroll
        for (int m = 1; m < 8; m <<= 1) {
            v0 += __shfl_xor(v0, m, 64);
            v1 += __shfl_xor(v1, m, 64);
            v2 += __shfl_xor(v2, m, 64);
        }
        if (e == 0 && gi < S) {
            const float wg = swgt[s2];
            rgb0 = fmaf(wg, 1.0f / (1.0f + __expf(-v0)), rgb0);
            rgb1 = fmaf(wg, 1.0f / (1.0f + __expf(-v1)), rgb1);
            rgb2 = fmaf(wg, 1.0f / (1.0f + __expf(-v2)), rgb2);
        }
    }

    // ---- final wave reduction: rgb (nonzero on e==0 lanes), depth, acc -----
    float u0 = rgb0, u1 = rgb1, u2 = rgb2, u3 = accD, u4 = accA;
    #pragma unroll
    for (int off = 32; off > 0; off >>= 1) {
        u0 += __shfl_down(u0, off, 64);
        u1 += __shfl_down(u1, off, 64);
        u2 += __shfl_down(u2, off, 64);
        u3 += __shfl_down(u3, off, 64);
        u4 += __shfl_down(u4, off, 64);
    }
    if (lane == 0) {
        out_rgb[r * 3 + 0] = u0;
        out_rgb[r * 3 + 1] = u1;
        out_rgb[r * 3 + 2] = u2;
        out_depth[r]       = u3;
        out_acc[r]         = u4;
    }
}

extern "C" void kernel_launch(void* const* d_in, const int* in_sizes, int n_in,
                              void* d_out, int out_size, void* d_ws, size_t ws_size,
                              hipStream_t stream) {
    const float* ray_o   = (const float*)d_in[0];
    const float* ray_d   = (const float*)d_in[1];
    const float* density = (const float*)d_in[2];
    const float* sh      = (const float*)d_in[3];
    const int R = in_sizes[0] / 3;

    float* out_rgb   = (float*)d_out;
    float* out_depth = out_rgb + (size_t)R * 3;
    float* out_acc   = out_depth + R;

    plenoxel_kernel<<<R, 64, 0, stream>>>(ray_o, ray_d, density, sh,
                                          out_rgb, out_depth, out_acc, R);
}

// Round 3
// 509.359 us; speedup vs baseline: 1.0928x; 1.0150x over previous
//
#include <hip/hip_runtime.h>
#include <math.h>

#define RES 160
#define NSAMP 128
#define NEAR_T 0.1f
#define FAR_T 10.0f
#define STEP ((FAR_T - NEAR_T) / (float)(NSAMP - 1))

typedef float float4v __attribute__((ext_vector_type(4)));

// corner k: xb = k>>2, yb = (k>>1)&1, zb = k&1 (reference order)
__device__ __forceinline__ void sample_geom8(
    const float ox, const float oy, const float oz,
    const float dx, const float dy, const float dz,
    const int s, int vidx[8], float w8[8])
{
    const float t = NEAR_T + STEP * (float)s;
    const float px = ox + t * dx, py = oy + t * dy, pz = oz + t * dz;
    float vx = (px + 1.0f) * 0.5f * (float)RES;
    float vy = (py + 1.0f) * 0.5f * (float)RES;
    float vz = (pz + 1.0f) * 0.5f * (float)RES;
    vx = fminf(fmaxf(vx, 0.0f), (float)(RES - 1));
    vy = fminf(fmaxf(vy, 0.0f), (float)(RES - 1));
    vz = fminf(fmaxf(vz, 0.0f), (float)(RES - 1));
    const float flx = floorf(vx), fly = floorf(vy), flz = floorf(vz);
    const int x0 = (int)flx, y0 = (int)fly, z0 = (int)flz;
    const int x1 = min(x0 + 1, RES - 1);
    const int y1 = min(y0 + 1, RES - 1);
    const int z1 = min(z0 + 1, RES - 1);
    const float fx = vx - flx, fy = vy - fly, fz = vz - flz;

    const float wx0 = 1.0f - fx, wx1 = fx;
    const float wy0 = 1.0f - fy, wy1 = fy;
    const float wz0 = 1.0f - fz, wz1 = fz;

    const int zy00 = (z0 * RES + y0) * RES;
    const int zy01 = (z0 * RES + y1) * RES;
    const int zy10 = (z1 * RES + y0) * RES;
    const int zy11 = (z1 * RES + y1) * RES;
    vidx[0] = zy00 + x0; w8[0] = wx0 * wy0 * wz0;
    vidx[1] = zy10 + x0; w8[1] = wx0 * wy0 * wz1;
    vidx[2] = zy01 + x0; w8[2] = wx0 * wy1 * wz0;
    vidx[3] = zy11 + x0; w8[3] = wx0 * wy1 * wz1;
    vidx[4] = zy00 + x1; w8[4] = wx1 * wy0 * wz0;
    vidx[5] = zy10 + x1; w8[5] = wx1 * wy0 * wz1;
    vidx[6] = zy01 + x1; w8[6] = wx1 * wy1 * wz0;
    vidx[7] = zy11 + x1; w8[7] = wx1 * wy1 * wz1;
}

// One ray per 128-thread block (2 waves). VGPR capped at 128 so 8 blocks
// (16 waves) stay resident per CU; 2x wave supply + 2-deep SH pipeline
// doubles outstanding scattered misses per CU vs the 1-wave version.
__global__ __launch_bounds__(128, 4) void plenoxel_kernel(
    const float* __restrict__ ray_o,
    const float* __restrict__ ray_d,
    const float* __restrict__ density,
    const float* __restrict__ sh,
    float* __restrict__ out_rgb,    // [R,3]
    float* __restrict__ out_depth,  // [R]
    float* __restrict__ out_acc,    // [R]
    int R)
{
    const int r    = blockIdx.x;
    const int tid  = threadIdx.x;   // 0..127
    const int wv   = tid >> 6;      // wave 0/1
    const int lane = tid & 63;
    const int g2   = tid >> 3;      // SH group 0..15
    const int e    = tid & 7;       // lane within SH group
    if (r >= R) return;

    __shared__ float swgt[NSAMP];
    __shared__ int   slist[NSAMP];
    __shared__ int   scnt[2];
    __shared__ float w0tot;
    __shared__ float partDA[2][2];
    __shared__ float partRGB[2][3];

    const float ox = ray_o[r * 3 + 0], oy = ray_o[r * 3 + 1], oz = ray_o[r * 3 + 2];
    const float dx = ray_d[r * 3 + 0], dy = ray_d[r * 3 + 1], dz = ray_d[r * 3 + 2];

    // per-ray SH deg-2 basis (block-uniform)
    const float dn  = sqrtf(dx * dx + dy * dy + dz * dz);
    const float inv = 1.0f / (dn + 1e-8f);
    const float nx = dx * inv, ny = dy * inv, nz = dz * inv;
    const float b0 = 0.28209479177387814f;
    const float b1 = -0.48860251190291987f * ny;
    const float b2 =  0.48860251190291987f * nz;
    const float b3 = -0.48860251190291987f * nx;
    const float b4 =  1.0925484305920792f * nx * ny;
    const float b5 = -1.0925484305920792f * ny * nz;
    const float b6 =  0.31539156525252005f * (2.0f * nz * nz - nx * nx - ny * ny);
    const float b7 = -1.0925484305920792f * nx * nz;
    const float b8 =  0.5462742152960396f * (nx * nx - ny * ny);

    // per-lane channel-masked basis vectors (lane e covers SH row floats
    // [offE, offE+3]; row layout: 0-8 = ch0, 9-17 = ch1, 18-26 = ch2)
    float4v bLo = {0.f, 0.f, 0.f, 0.f}, bHi = {0.f, 0.f, 0.f, 0.f};
    int chLo = 3, chHi = 3;   // 3 = none
    switch (e) {
        case 0: bLo = (float4v){b0, b1, b2, b3}; chLo = 0; break;
        case 1: bLo = (float4v){b4, b5, b6, b7}; chLo = 0; break;
        case 2: bLo = (float4v){b8, 0.f, 0.f, 0.f}; bHi = (float4v){0.f, b0, b1, b2};
                chLo = 0; chHi = 1; break;
        case 3: bLo = (float4v){b3, b4, b5, b6}; chLo = 1; break;
        case 4: bLo = (float4v){b7, b8, 0.f, 0.f}; bHi = (float4v){0.f, 0.f, b0, b1};
                chLo = 1; chHi = 2; break;
        case 5: bLo = (float4v){b2, b3, b4, b5}; chLo = 2; break;
        case 6: bLo = (float4v){0.f, b6, b7, b8}; chLo = 2; break; // float 23 dup zeroed
        default: break;                                            // lane 7: no SH work
    }
    const int offE = (e >= 6) ? 23 : 4 * e;

    // ---- Phase A: density, 1 sample per thread (128 threads = 128 samples) -
    float dsum = 0.0f;
    {
        int vidx[8]; float w8[8];
        sample_geom8(ox, oy, oz, dx, dy, dz, tid, vidx, w8);
        #pragma unroll
        for (int k = 0; k < 8; ++k) dsum = fmaf(w8[k], density[vidx[k]], dsum);
    }

    // ---- Transmittance scan across 2 waves ---------------------------------
    const float ts   = NEAR_T + STEP * (float)tid;
    const float dist = ((tid == NSAMP - 1) ? 1e10f : STEP) * dn;
    const float alpha = 1.0f - __expf(-fmaxf(dsum, 0.0f) * dist);
    const float om = 1.0f - alpha + 1e-10f;

    float incl = om;
    #pragma unroll
    for (int off = 1; off < 64; off <<= 1) {
        const float u = __shfl_up(incl, off, 64);
        incl *= (lane >= off) ? u : 1.0f;
    }
    if (tid == 63) w0tot = incl;
    __syncthreads();

    float excl = __shfl_up(incl, 1, 64);
    if (lane == 0) excl = 1.0f;
    const float scale = wv ? w0tot : 1.0f;
    const float wgt = alpha * excl * scale;
    swgt[tid] = wgt;

    // depth/acc partials per wave (all samples — exact w.r.t. the zero-skip)
    {
        float u3 = wgt * ts, u4 = wgt;
        #pragma unroll
        for (int off = 32; off > 0; off >>= 1) {
            u3 += __shfl_down(u3, off, 64);
            u4 += __shfl_down(u4, off, 64);
        }
        if (lane == 0) { partDA[wv][0] = u3; partDA[wv][1] = u4; }
    }

    // ---- survivor compaction (exact-zero skip) -----------------------------
    const bool flag = (wgt != 0.0f);
    const unsigned long long mask = __ballot(flag);
    const int rank = __popcll(mask & ((1ull << lane) - 1ull));
    if (lane == 0) scnt[wv] = __popcll(mask);
    __syncthreads();
    const int base = wv ? scnt[0] : 0;
    if (flag) slist[base + rank] = tid;
    __syncthreads();
    const int S = scnt[0] + scnt[1];

    // ---- Phase B: SH gather, 16 groups/iter, 2-deep software pipeline ------
    float rgb0 = 0.f, rgb1 = 0.f, rgb2 = 0.f;
    const int nIter = (S + 15) >> 4;

    float4v rA[8] = {}; float wA[8]; int s2A = 0; bool vA_ = false;
    float4v rB[8] = {}; float wB[8]; int s2B = 0; bool vB_ = false;

#define SH_LOAD(J, S2, WW, RR, VV) do {                                        \
        const int gi_ = (J) * 16 + g2;                                         \
        VV = (gi_ < S);                                                        \
        S2 = VV ? slist[gi_] : 0;                                              \
        int vidx_[8];                                                          \
        sample_geom8(ox, oy, oz, dx, dy, dz, S2, vidx_, WW);                   \
        if (VV && e < 7) {                                                     \
            _Pragma("unroll")                                                  \
            for (int k_ = 0; k_ < 8; ++k_)                                     \
                RR[k_] = *(const float4v*)(sh + (size_t)vidx_[k_] * 27 + offE);\
        }                                                                      \
    } while (0)

#define SH_COMPUTE(S2, WW, RR, VV) do {                                        \
        float accLo_ = 0.f, accHi_ = 0.f;                                      \
        _Pragma("unroll")                                                      \
        for (int k_ = 0; k_ < 8; ++k_) {                                       \
            const float tl_ = RR[k_].x * bLo.x + RR[k_].y * bLo.y +            \
                              RR[k_].z * bLo.z + RR[k_].w * bLo.w;             \
            const float th_ = RR[k_].x * bHi.x + RR[k_].y * bHi.y +            \
                              RR[k_].z * bHi.z + RR[k_].w * bHi.w;             \
            accLo_ = fmaf(tl_, WW[k_], accLo_);                                \
            accHi_ = fmaf(th_, WW[k_], accHi_);                                \
        }                                                                      \
        float v0_ = ((chLo == 0) ? accLo_ : 0.f) + ((chHi == 0) ? accHi_ : 0.f);\
        float v1_ = ((chLo == 1) ? accLo_ : 0.f) + ((chHi == 1) ? accHi_ : 0.f);\
        float v2_ = ((chLo == 2) ? accLo_ : 0.f) + ((chHi == 2) ? accHi_ : 0.f);\
        _Pragma("unroll")                                                      \
        for (int m_ = 1; m_ < 8; m_ <<= 1) {                                   \
            v0_ += __shfl_xor(v0_, m_, 64);                                    \
            v1_ += __shfl_xor(v1_, m_, 64);                                    \
            v2_ += __shfl_xor(v2_, m_, 64);                                    \
        }                                                                      \
        if (e == 0 && VV) {                                                    \
            const float wg_ = swgt[S2];                                        \
            rgb0 = fmaf(wg_, 1.0f / (1.0f + __expf(-v0_)), rgb0);              \
            rgb1 = fmaf(wg_, 1.0f / (1.0f + __expf(-v1_)), rgb1);              \
            rgb2 = fmaf(wg_, 1.0f / (1.0f + __expf(-v2_)), rgb2);              \
        }                                                                      \
    } while (0)

    if (nIter > 0) {
        SH_LOAD(0, s2A, wA, rA, vA_);
        for (int i = 0; i < nIter; i += 2) {
            if (i + 1 < nIter) SH_LOAD(i + 1, s2B, wB, rB, vB_);
            SH_COMPUTE(s2A, wA, rA, vA_);
            if (i + 1 < nIter) {
                if (i + 2 < nIter) SH_LOAD(i + 2, s2A, wA, rA, vA_);
                SH_COMPUTE(s2B, wB, rB, vB_);
            }
        }
    }
#undef SH_LOAD
#undef SH_COMPUTE

    // ---- final reductions: rgb per wave, then combine with depth/acc -------
    {
        float u0 = rgb0, u1 = rgb1, u2 = rgb2;
        #pragma unroll
        for (int off = 32; off > 0; off >>= 1) {
            u0 += __shfl_down(u0, off, 64);
            u1 += __shfl_down(u1, off, 64);
            u2 += __shfl_down(u2, off, 64);
        }
        if (lane == 0) {
            partRGB[wv][0] = u0; partRGB[wv][1] = u1; partRGB[wv][2] = u2;
        }
    }
    __syncthreads();
    if (tid == 0) {
        out_rgb[r * 3 + 0] = partRGB[0][0] + partRGB[1][0];
        out_rgb[r * 3 + 1] = partRGB[0][1] + partRGB[1][1];
        out_rgb[r * 3 + 2] = partRGB[0][2] + partRGB[1][2];
        out_depth[r]       = partDA[0][0] + partDA[1][0];
        out_acc[r]         = partDA[0][1] + partDA[1][1];
    }
}

extern "C" void kernel_launch(void* const* d_in, const int* in_sizes, int n_in,
                              void* d_out, int out_size, void* d_ws, size_t ws_size,
                              hipStream_t stream) {
    const float* ray_o   = (const float*)d_in[0];
    const float* ray_d   = (const float*)d_in[1];
    const float* density = (const float*)d_in[2];
    const float* sh      = (const float*)d_in[3];
    const int R = in_sizes[0] / 3;

    float* out_rgb   = (float*)d_out;
    float* out_depth = out_rgb + (size_t)R * 3;
    float* out_acc   = out_depth + R;

    plenoxel_kernel<<<R, 128, 0, stream>>>(ray_o, ray_d, density, sh,
                                           out_rgb, out_depth, out_acc, R);
}